// Round 20
// baseline (4321.280 us; speedup 1.0000x reference)
//
#include <hip/hip_runtime.h>
#include <hip/hip_bf16.h>
#include <stdint.h>

typedef float f32x4 __attribute__((ext_vector_type(4)));
typedef float f32x16 __attribute__((ext_vector_type(16)));
typedef int i32x4 __attribute__((ext_vector_type(4)));
typedef int i32x8 __attribute__((ext_vector_type(8)));
typedef long i64;

#define BM 256
#define BN 256
#define BKB 64   // K elements (=bytes, fp8) per tile step

// 16B-chunk slot = chunk ^ swz(row); period 16 covers the 32-row frag read.
__device__ __host__ __forceinline__ int swz(int r) {
  return ((r >> 1) ^ (r >> 3)) & 3;
}

// ---------------- pre-quant: fp32 (bf16-valued) -> fp8 e4m3fn, LINEAR -------
__global__ __launch_bounds__(256) void quant_fp8_from_f32(
    const float* __restrict__ in, const float* __restrict__ scale,
    uint8_t* __restrict__ out, int n16) {
  const int i = blockIdx.x * blockDim.x + threadIdx.x;
  if (i >= n16) return;
  const float inv_s = 1.0f / scale[0];
  const float* p = in + (i64)i * 16;
  f32x4 v[4];
  v[0] = *(const f32x4*)p;
  v[1] = *(const f32x4*)(p + 4);
  v[2] = *(const f32x4*)(p + 8);
  v[3] = *(const f32x4*)(p + 12);
  uint32_t w[4];
#pragma unroll
  for (int q = 0; q < 4; q++) {
    float f0 = fminf(fmaxf(v[q][0] * inv_s, -448.f), 448.f);
    float f1 = fminf(fmaxf(v[q][1] * inv_s, -448.f), 448.f);
    float f2 = fminf(fmaxf(v[q][2] * inv_s, -448.f), 448.f);
    float f3 = fminf(fmaxf(v[q][3] * inv_s, -448.f), 448.f);
    int r = 0;
    r = __builtin_amdgcn_cvt_pk_fp8_f32(f0, f1, r, false);
    r = __builtin_amdgcn_cvt_pk_fp8_f32(f2, f3, r, true);
    w[q] = (uint32_t)r;
  }
  ((uint4*)out)[i] = make_uint4(w[0], w[1], w[2], w[3]);
}

__device__ __forceinline__ void gload_lds16(const void* g, void* l) {
  __builtin_amdgcn_global_load_lds(
      (const __attribute__((address_space(1))) uint32_t*)g,
      (__attribute__((address_space(3))) uint32_t*)l, 16, 0, 0);
}

__device__ __forceinline__ float bf16_rne_f32(float f) {
  union { float f; uint32_t u; } c; c.f = f;
  uint32_t lsb = (c.u >> 16) & 1u;
  c.u += 0x7FFFu + lsb;
  c.u &= 0xFFFF0000u;
  return c.f;
}

// ---------------- fp8 GEMM via MX-scaled 32x32x64 MFMA (scales = 1.0) -------
// 256x256 tile, 4 waves (2x2), wave-tile 128x128: 16 b128 reads feed 16 MFMA
// (16B/MFMA vs 24B at 128x64 wave-tile) -- LDS read burst shrinks 1.5x.
// Double-buffered LDS (64KB), ONE barrier per K-step:
//   [barrier -> stage tile t+1 (8 gloads/thread) -> vmcnt(8) -> ds_read+MFMA]
// Overwrite fence: a wave passes the barrier only after issuing its MFMAs,
// which requires its ds_reads consumed; the buffer staged at t was last read
// at t-1, fenced by the top-of-t barrier. vmcnt counts per-THREAD instrs:
// 8 in flight (next tile) after the wait.
__global__ __launch_bounds__(256, 2) void gemm_fp8_mx(
    const uint8_t* __restrict__ Aq, const uint8_t* __restrict__ Bq,
    const float* __restrict__ bias,
    const float* __restrict__ xs, const float* __restrict__ wsc,
    float* __restrict__ C, int M, int N, int K) {
  __shared__ uint8_t sA[2][BM * BKB];   // 2 x 16 KB
  __shared__ uint8_t sB[2][BN * BKB];   // 2 x 16 KB

  const int nbn = N / BN;
  int bid = blockIdx.x;
  { int cpx = gridDim.x >> 3; bid = (bid & 7) * cpx + (bid >> 3); }  // XCD swizzle
  const int bm = bid / nbn;
  const int bn = bid % nbn;

  const int t = threadIdx.x, lane = t & 63, wave = t >> 6;
  const int wm = (wave >> 1) * 128;   // 2x2 waves, 128x128 each
  const int wn = (wave & 1) * 128;
  const int g = lane >> 5;            // K-half group
  const int r31 = lane & 31;

  f32x16 acc[4][4];
#pragma unroll
  for (int i = 0; i < 4; i++)
#pragma unroll
    for (int j = 0; j < 4; j++) acc[i][j] = (f32x16)0.f;

  // ---- staging: thread t stages chunk (t&3) of rows (t>>2)+64j, j=0..3 ----
  // LDS dest for gload j = sX + j*4096 + t*16 (linear: wave base + lane*16).
  const int srow = t >> 2;            // 0..63
  const int c16 = t & 3;
  i64 src[4];
#pragma unroll
  for (int j = 0; j < 4; j++) {
    const int row = srow + 64 * j;
    src[j] = (i64)row * K + ((c16 ^ swz(row)) << 4);
  }
  const uint8_t* gA = Aq + (i64)(bm * BM) * K;
  const uint8_t* gB = Bq + (i64)(bn * BN) * K;

  // ---- fragment read offsets (hoisted) ----
  int aoff[4][2], boff[4][2];
#pragma unroll
  for (int i = 0; i < 4; i++) {
    const int ra = wm + i * 32 + r31;
    const int sa_ = swz(ra);
    aoff[i][0] = ra * 64 + (((2 * g + 0) ^ sa_) << 4);
    aoff[i][1] = ra * 64 + (((2 * g + 1) ^ sa_) << 4);
    const int rb = wn + i * 32 + r31;
    const int sb_ = swz(rb);
    boff[i][0] = rb * 64 + (((2 * g + 0) ^ sb_) << 4);
    boff[i][1] = rb * 64 + (((2 * g + 1) ^ sb_) << 4);
  }

  const int NT = K / BKB;
  // prologue: stage tile 0 into buffer 0 (8 loads/thread in flight)
#pragma unroll
  for (int j = 0; j < 4; j++) {
    gload_lds16(gA + src[j], &sA[0][t * 16 + j * 4096]);
    gload_lds16(gB + src[j], &sB[0][t * 16 + j * 4096]);
  }

  int cur = 0;
  for (int it = 0; it < NT; ++it) {
    // all waves consumed their reads of buf[cur^1] (iter it-1) before here
    __builtin_amdgcn_s_barrier();
    if (it + 1 < NT) {
      const i64 kt = (i64)(it + 1) * BKB;
      const int nxt = cur ^ 1;
#pragma unroll
      for (int j = 0; j < 4; j++) {
        gload_lds16(gA + src[j] + kt, &sA[nxt][t * 16 + j * 4096]);
        gload_lds16(gB + src[j] + kt, &sB[nxt][t * 16 + j * 4096]);
      }
      asm volatile("s_waitcnt vmcnt(8)" ::: "memory");   // tile `it` landed
    } else {
      asm volatile("s_waitcnt vmcnt(0)" ::: "memory");
    }

    union { i32x4 h[2]; i32x8 v; } ua[4], ub[4];
#pragma unroll
    for (int i = 0; i < 4; i++) {
      ua[i].h[0] = *(const i32x4*)(&sA[cur][0] + aoff[i][0]);
      ua[i].h[1] = *(const i32x4*)(&sA[cur][0] + aoff[i][1]);
      ub[i].h[0] = *(const i32x4*)(&sB[cur][0] + boff[i][0]);
      ub[i].h[1] = *(const i32x4*)(&sB[cur][0] + boff[i][1]);
    }
#pragma unroll
    for (int i = 0; i < 4; i++)
#pragma unroll
      for (int j = 0; j < 4; j++)
        acc[i][j] = __builtin_amdgcn_mfma_scale_f32_32x32x64_f8f6f4(
            ua[i].v, ub[j].v, acc[i][j],
            0, 0,          // cbsz=fp8(e4m3), blgp=fp8(e4m3)
            0, 127,        // scale_a = e8m0 1.0
            0, 127);       // scale_b = e8m0 1.0
    cur ^= 1;
  }

  // ---- epilogue: bf16_rne(acc*(sx*sw) + bias) stored as FP32 -------------
  // 32x32 C/D layout (m74/m101): col = lane&31, row = (reg&3)+8*(reg>>2)+4*g
  const float sc = xs[0] * wsc[0];
#pragma unroll
  for (int j = 0; j < 4; j++) {
    const int col = bn * BN + wn + j * 32 + r31;
    const float bv = bias[col];
#pragma unroll
    for (int i = 0; i < 4; i++) {
      const int rowbase = bm * BM + wm + i * 32 + 4 * g;
#pragma unroll
      for (int reg = 0; reg < 16; reg++) {
        const int row = rowbase + (reg & 3) + 8 * (reg >> 2);
        C[(i64)row * N + col] = bf16_rne_f32(acc[i][j][reg] * sc + bv);
      }
    }
  }
}

extern "C" void kernel_launch(void* const* d_in, const int* in_sizes, int n_in,
                              void* d_out, int out_size, void* d_ws, size_t ws_size,
                              hipStream_t stream) {
  // Verified I/O model (R11 oracle + R12-R19 passes): declared order, element
  // counts, ALL buffers fp32-stored bf16-valued, output fp32.
  const float* x = (const float*)d_in[0];
  const float* w = (const float*)d_in[1];
  const float* bias = (const float*)d_in[2];
  const float* x_scale = (const float*)d_in[3];
  const float* w_scale = (const float*)d_in[4];

  const int N = in_sizes[2];
  const int K = in_sizes[1] / N;
  const int M = in_sizes[0] / K;

  uint8_t* xq = (uint8_t*)d_ws;                     // M*K = 32 MB
  uint8_t* wq = (uint8_t*)d_ws + (size_t)M * K;     // N*K = 64 MB

  {
    const int n16 = (M * K) / 16;
    quant_fp8_from_f32<<<(n16 + 255) / 256, 256, 0, stream>>>(x, x_scale, xq, n16);
  }
  {
    const int n16 = (int)(((i64)N * K) / 16);
    quant_fp8_from_f32<<<(n16 + 255) / 256, 256, 0, stream>>>(w, w_scale, wq, n16);
  }

  dim3 grid((M / BM) * (N / BN));
  gemm_fp8_mx<<<grid, 256, 0, stream>>>(
      xq, wq, bias, x_scale, w_scale, (float*)d_out, M, N, K);
}

// Round 21
// 3684.917 us; speedup vs baseline: 1.1727x; 1.1727x over previous
//
#include <hip/hip_runtime.h>
#include <hip/hip_bf16.h>
#include <stdint.h>

typedef float f32x4 __attribute__((ext_vector_type(4)));
typedef float f32x16 __attribute__((ext_vector_type(16)));
typedef int i32x4 __attribute__((ext_vector_type(4)));
typedef int i32x8 __attribute__((ext_vector_type(8)));
typedef long i64;

#define BM 256
#define BN 256
#define TILE 16384   // bytes per K-tile (64 fp8) per matrix

// 16B-chunk slot = chunk ^ swz(row); period 16 covers the 32-row frag read.
__device__ __host__ __forceinline__ int swz(int r) {
  return ((r >> 1) ^ (r >> 3)) & 3;
}

// ---------------- pre-quant: fp32 (bf16-valued) -> fp8 e4m3fn, LINEAR -------
__global__ __launch_bounds__(256) void quant_fp8_from_f32(
    const float* __restrict__ in, const float* __restrict__ scale,
    uint8_t* __restrict__ out, int n16) {
  const int i = blockIdx.x * blockDim.x + threadIdx.x;
  if (i >= n16) return;
  const float inv_s = 1.0f / scale[0];
  const float* p = in + (i64)i * 16;
  f32x4 v[4];
  v[0] = *(const f32x4*)p;
  v[1] = *(const f32x4*)(p + 4);
  v[2] = *(const f32x4*)(p + 8);
  v[3] = *(const f32x4*)(p + 12);
  uint32_t w[4];
#pragma unroll
  for (int q = 0; q < 4; q++) {
    float f0 = fminf(fmaxf(v[q][0] * inv_s, -448.f), 448.f);
    float f1 = fminf(fmaxf(v[q][1] * inv_s, -448.f), 448.f);
    float f2 = fminf(fmaxf(v[q][2] * inv_s, -448.f), 448.f);
    float f3 = fminf(fmaxf(v[q][3] * inv_s, -448.f), 448.f);
    int r = 0;
    r = __builtin_amdgcn_cvt_pk_fp8_f32(f0, f1, r, false);
    r = __builtin_amdgcn_cvt_pk_fp8_f32(f2, f3, r, true);
    w[q] = (uint32_t)r;
  }
  ((uint4*)out)[i] = make_uint4(w[0], w[1], w[2], w[3]);
}

__device__ __forceinline__ void gload_lds16(const void* g, void* l) {
  __builtin_amdgcn_global_load_lds(
      (const __attribute__((address_space(1))) uint32_t*)g,
      (__attribute__((address_space(3))) uint32_t*)l, 16, 0, 0);
}

__device__ __forceinline__ float bf16_rne_f32(float f) {
  union { float f; uint32_t u; } c; c.f = f;
  uint32_t lsb = (c.u >> 16) & 1u;
  c.u += 0x7FFFu + lsb;
  c.u &= 0xFFFF0000u;
  return c.f;
}

// ---------------- fp8 GEMM, 8-phase schedule (m201 port, MX 32x32x64) -------
// 256x256 tile, 8 waves (2Mx4N), wave-tile 128x64, acc[4][2] f32x16 (128 reg).
// Iter = 2 K-tiles of 64. 4 LDS slots (128 KB): even iters read slots {0,1},
// stage {2,3}; odd iters swap. Per K-tile 4 phases:
//   { ds_read subtile ; 1 gload (next iter) ; barrier ;
//     setprio(1) 2x MFMA setprio(0) ; barrier }
// Next iter's 8 gloads stay in flight across ALL phase barriers (T4);
// drained once at iter-top via vmcnt(0) with a full iter of slack.
__global__ __launch_bounds__(512, 2) void gemm_fp8_mx(
    const uint8_t* __restrict__ Aq, const uint8_t* __restrict__ Bq,
    const float* __restrict__ bias,
    const float* __restrict__ xs, const float* __restrict__ wsc,
    float* __restrict__ C, int M, int N, int K) {
  __shared__ uint8_t sA[4][TILE];   // 64 KB
  __shared__ uint8_t sB[4][TILE];   // 64 KB

  const int nbn = N / BN;
  int bid = blockIdx.x;
  { int cpx = gridDim.x >> 3; bid = (bid & 7) * cpx + (bid >> 3); }  // XCD swizzle
  const int bm = bid / nbn;
  const int bn = bid % nbn;

  const int t = threadIdx.x, lane = t & 63, wave = t >> 6;
  const int wm = (wave >> 2) * 128;   // 2 wave-rows of 128
  const int wn = (wave & 3) * 64;     // 4 wave-cols of 64
  const int g = lane >> 5;            // K-half group
  const int r31 = lane & 31;

  f32x16 acc[4][2];
#pragma unroll
  for (int i = 0; i < 4; i++)
#pragma unroll
    for (int j = 0; j < 2; j++) acc[i][j] = (f32x16)0.f;

  // ---- staging geometry: thread t stages chunk (t&3) of rows t/4, t/4+128 ----
  const int srow = t >> 2;            // 0..127
  const int c16 = t & 3;
  const i64 srcR0 = (i64)srow * K + ((c16 ^ swz(srow)) << 4);
  const i64 srcR1 = (i64)(srow + 128) * K + ((c16 ^ swz(srow + 128)) << 4);
  const uint8_t* gA = Aq + (i64)(bm * BM) * K;
  const uint8_t* gB = Bq + (i64)(bn * BN) * K;
  const int d0 = t * 16;              // LDS dest round 0
  const int d1 = t * 16 + 8192;       // LDS dest round 1

  // ---- fragment read offsets within a tile (hoisted) ----
  int aoff[4][2], boff[2][2];
#pragma unroll
  for (int i = 0; i < 4; i++) {
    const int ra = wm + i * 32 + r31;
    const int sa_ = swz(ra);
    aoff[i][0] = ra * 64 + (((2 * g + 0) ^ sa_) << 4);
    aoff[i][1] = ra * 64 + (((2 * g + 1) ^ sa_) << 4);
  }
#pragma unroll
  for (int j = 0; j < 2; j++) {
    const int rb = wn + j * 32 + r31;
    const int sb_ = swz(rb);
    boff[j][0] = rb * 64 + (((2 * g + 0) ^ sb_) << 4);
    boff[j][1] = rb * 64 + (((2 * g + 1) ^ sb_) << 4);
  }

  const int NTI = K / 128;            // iters (2 K-tiles each)

  // prologue: stage tiles 0,1 into slots 0,1 (8 gloads/thread in flight)
  gload_lds16(gA + srcR0, &sA[0][d0]);
  gload_lds16(gA + srcR1, &sA[0][d1]);
  gload_lds16(gB + srcR0, &sB[0][d0]);
  gload_lds16(gB + srcR1, &sB[0][d1]);
  gload_lds16(gA + srcR0 + 64, &sA[1][d0]);
  gload_lds16(gA + srcR1 + 64, &sA[1][d1]);
  gload_lds16(gB + srcR0 + 64, &sB[1][d0]);
  gload_lds16(gB + srcR1 + 64, &sB[1][d1]);

#define RD_A(slot, i, h) (*(const i32x4*)(&sA[slot][0] + aoff[i][h]))
#define RD_B(slot, j, h) (*(const i32x4*)(&sB[slot][0] + boff[j][h]))
#define MFMA2(ci, cj, uai, ubj)                                              \
  acc[ci][cj] = __builtin_amdgcn_mfma_scale_f32_32x32x64_f8f6f4(             \
      uai.v, ubj.v, acc[ci][cj], 0, 0, 0, 127, 0, 127);
#define BAR() __builtin_amdgcn_s_barrier()
#define PRIO1() __builtin_amdgcn_s_setprio(1)
#define PRIO0() __builtin_amdgcn_s_setprio(0)

  // one K-tile = 4 phases; GL* = staging statement or nothing
#define KTILE(RS, GL0, GL1, GL2, GL3)                                        \
  {                                                                          \
    union { i32x4 h[2]; i32x8 v; } ua0, ua1, ua2, ua3, ub0, ub1;             \
    /* ph0 */                                                                \
    ua0.h[0] = RD_A(RS, 0, 0); ua0.h[1] = RD_A(RS, 0, 1);                    \
    ua1.h[0] = RD_A(RS, 1, 0); ua1.h[1] = RD_A(RS, 1, 1);                    \
    ub0.h[0] = RD_B(RS, 0, 0); ub0.h[1] = RD_B(RS, 0, 1);                    \
    GL0;                                                                     \
    BAR(); PRIO1(); MFMA2(0, 0, ua0, ub0); MFMA2(1, 0, ua1, ub0);            \
    PRIO0(); BAR();                                                          \
    /* ph1 */                                                                \
    ub1.h[0] = RD_B(RS, 1, 0); ub1.h[1] = RD_B(RS, 1, 1);                    \
    GL1;                                                                     \
    BAR(); PRIO1(); MFMA2(0, 1, ua0, ub1); MFMA2(1, 1, ua1, ub1);            \
    PRIO0(); BAR();                                                          \
    /* ph2 */                                                                \
    ua2.h[0] = RD_A(RS, 2, 0); ua2.h[1] = RD_A(RS, 2, 1);                    \
    ua3.h[0] = RD_A(RS, 3, 0); ua3.h[1] = RD_A(RS, 3, 1);                    \
    GL2;                                                                     \
    BAR(); PRIO1(); MFMA2(2, 0, ua2, ub0); MFMA2(3, 0, ua3, ub0);            \
    PRIO0(); BAR();                                                          \
    /* ph3 */                                                                \
    GL3;                                                                     \
    BAR(); PRIO1(); MFMA2(2, 1, ua2, ub1); MFMA2(3, 1, ua3, ub1);            \
    PRIO0(); BAR();                                                          \
  }

  for (int it = 0; it < NTI; ++it) {
    const int rs = (it & 1) << 1;       // read slots rs, rs+1
    const int ws_ = ((it & 1) ^ 1) << 1; // stage slots ws_, ws_+1
    const bool pf = (it + 1 < NTI);
    const i64 k0 = (i64)(it + 1) * 128;  // next iter's first tile k-offset

    // all 8 loads issued last iter (this iter's tiles) must have landed
    asm volatile("s_waitcnt vmcnt(0)" ::: "memory");
    BAR();

    // K-tile 0 of this iter (slot rs); stage next iter's tile ws_
    if (pf) {
      KTILE(rs,
            gload_lds16(gA + srcR0 + k0, &sA[ws_][d0]),
            gload_lds16(gA + srcR1 + k0, &sA[ws_][d1]),
            gload_lds16(gB + srcR0 + k0, &sB[ws_][d0]),
            gload_lds16(gB + srcR1 + k0, &sB[ws_][d1]));
      // K-tile 1 (slot rs+1); stage next iter's tile ws_+1 (k0+64)
      KTILE(rs + 1,
            gload_lds16(gA + srcR0 + k0 + 64, &sA[ws_ + 1][d0]),
            gload_lds16(gA + srcR1 + k0 + 64, &sA[ws_ + 1][d1]),
            gload_lds16(gB + srcR0 + k0 + 64, &sB[ws_ + 1][d0]),
            gload_lds16(gB + srcR1 + k0 + 64, &sB[ws_ + 1][d1]));
    } else {
      KTILE(rs, , , , );
      KTILE(rs + 1, , , , );
    }
  }

  // ---- epilogue: bf16_rne(acc*(sx*sw) + bias) stored as FP32 -------------
  // 32x32 C/D layout (m74/m101): col = lane&31, row = (reg&3)+8*(reg>>2)+4*g
  const float sc = xs[0] * wsc[0];
#pragma unroll
  for (int j = 0; j < 2; j++) {
    const int col = bn * BN + wn + j * 32 + r31;
    const float bv = bias[col];
#pragma unroll
    for (int i = 0; i < 4; i++) {
      const int rowbase = bm * BM + wm + i * 32 + 4 * g;
#pragma unroll
      for (int reg = 0; reg < 16; reg++) {
        const int row = rowbase + (reg & 3) + 8 * (reg >> 2);
        C[(i64)row * N + col] = bf16_rne_f32(acc[i][j][reg] * sc + bv);
      }
    }
  }
}

extern "C" void kernel_launch(void* const* d_in, const int* in_sizes, int n_in,
                              void* d_out, int out_size, void* d_ws, size_t ws_size,
                              hipStream_t stream) {
  // Verified I/O model (R11 oracle + R12-R19 passes): declared order, element
  // counts, ALL buffers fp32-stored bf16-valued, output fp32.
  const float* x = (const float*)d_in[0];
  const float* w = (const float*)d_in[1];
  const float* bias = (const float*)d_in[2];
  const float* x_scale = (const float*)d_in[3];
  const float* w_scale = (const float*)d_in[4];

  const int N = in_sizes[2];
  const int K = in_sizes[1] / N;
  const int M = in_sizes[0] / K;

  uint8_t* xq = (uint8_t*)d_ws;                     // M*K = 32 MB
  uint8_t* wq = (uint8_t*)d_ws + (size_t)M * K;     // N*K = 64 MB

  {
    const int n16 = (M * K) / 16;
    quant_fp8_from_f32<<<(n16 + 255) / 256, 256, 0, stream>>>(x, x_scale, xq, n16);
  }
  {
    const int n16 = (int)(((i64)N * K) / 16);
    quant_fp8_from_f32<<<(n16 + 255) / 256, 256, 0, stream>>>(w, w_scale, wq, n16);
  }

  dim3 grid((M / BM) * (N / BN));
  gemm_fp8_mx<<<grid, 512, 0, stream>>>(
      xq, wq, bias, x_scale, w_scale, (float*)d_out, M, N, K);
}

// Round 22
// 2658.828 us; speedup vs baseline: 1.6253x; 1.3859x over previous
//
#include <hip/hip_runtime.h>
#include <hip/hip_bf16.h>
#include <stdint.h>

typedef float f32x4 __attribute__((ext_vector_type(4)));
typedef float f32x16 __attribute__((ext_vector_type(16)));
typedef int i32x4 __attribute__((ext_vector_type(4)));
typedef int i32x8 __attribute__((ext_vector_type(8)));
typedef long i64;

#define BM 256
#define BN 256
#define TILE 16384   // bytes per K-tile (64 fp8) per matrix

// 16B-chunk slot = chunk ^ swz(row); period 16 covers the 32-row frag read.
__device__ __host__ __forceinline__ int swz(int r) {
  return ((r >> 1) ^ (r >> 3)) & 3;
}

// ---------------- pre-quant: fp32 (bf16-valued) -> fp8 e4m3fn, LINEAR -------
__global__ __launch_bounds__(256) void quant_fp8_from_f32(
    const float* __restrict__ in, const float* __restrict__ scale,
    uint8_t* __restrict__ out, int n16) {
  const int i = blockIdx.x * blockDim.x + threadIdx.x;
  if (i >= n16) return;
  const float inv_s = 1.0f / scale[0];
  const float* p = in + (i64)i * 16;
  f32x4 v[4];
  v[0] = *(const f32x4*)p;
  v[1] = *(const f32x4*)(p + 4);
  v[2] = *(const f32x4*)(p + 8);
  v[3] = *(const f32x4*)(p + 12);
  uint32_t w[4];
#pragma unroll
  for (int q = 0; q < 4; q++) {
    float f0 = fminf(fmaxf(v[q][0] * inv_s, -448.f), 448.f);
    float f1 = fminf(fmaxf(v[q][1] * inv_s, -448.f), 448.f);
    float f2 = fminf(fmaxf(v[q][2] * inv_s, -448.f), 448.f);
    float f3 = fminf(fmaxf(v[q][3] * inv_s, -448.f), 448.f);
    int r = 0;
    r = __builtin_amdgcn_cvt_pk_fp8_f32(f0, f1, r, false);
    r = __builtin_amdgcn_cvt_pk_fp8_f32(f2, f3, r, true);
    w[q] = (uint32_t)r;
  }
  ((uint4*)out)[i] = make_uint4(w[0], w[1], w[2], w[3]);
}

__device__ __forceinline__ void gload_lds16(const void* g, void* l) {
  __builtin_amdgcn_global_load_lds(
      (const __attribute__((address_space(1))) uint32_t*)g,
      (__attribute__((address_space(3))) uint32_t*)l, 16, 0, 0);
}

__device__ __forceinline__ float bf16_rne_f32(float f) {
  union { float f; uint32_t u; } c; c.f = f;
  uint32_t lsb = (c.u >> 16) & 1u;
  c.u += 0x7FFFu + lsb;
  c.u &= 0xFFFF0000u;
  return c.f;
}

// ---------------- fp8 GEMM, 8-phase schedule, register-lean ----------------
// 256x256 tile, 8 waves (2Mx4N), wave-tile 128x64, acc[4][2] f32x16.
// Column-pair phase order: ub0,ub1 persist (16 regs); ONE ua (8 regs) refilled
// per phase -> max operand liveness ~24-32 regs (R21's 48-reg 6-union liveness
// blew the 256-reg/wave cap at 2 waves/SIMD and spilled 12 GB to scratch).
// Phase = { ds_read ua_i ; 1 staged gload ; barrier ; setprio1 ;
//           MFMA (i,0),(i,1) ; setprio0 ; barrier }.
// T4 counted waits: each KTILE ends with vmcnt(4) BEFORE its trailing barrier
// (drains the next-needed tile's 4 loads; the 4 just-issued stay in flight;
// the barrier makes the per-wave drains collective).
__global__ __launch_bounds__(512, 2) void gemm_fp8_mx(
    const uint8_t* __restrict__ Aq, const uint8_t* __restrict__ Bq,
    const float* __restrict__ bias,
    const float* __restrict__ xs, const float* __restrict__ wsc,
    float* __restrict__ C, int M, int N, int K) {
  __shared__ uint8_t sA[4][TILE];   // 64 KB
  __shared__ uint8_t sB[4][TILE];   // 64 KB

  const int nbn = N / BN;
  int bid = blockIdx.x;
  { int cpx = gridDim.x >> 3; bid = (bid & 7) * cpx + (bid >> 3); }  // XCD swizzle
  const int bm = bid / nbn;
  const int bn = bid % nbn;

  const int t = threadIdx.x, lane = t & 63, wave = t >> 6;
  const int wm = (wave >> 2) * 128;   // 2 wave-rows of 128
  const int wn = (wave & 3) * 64;     // 4 wave-cols of 64
  const int g = lane >> 5;            // K-half group
  const int r31 = lane & 31;

  f32x16 acc[4][2];
#pragma unroll
  for (int i = 0; i < 4; i++)
#pragma unroll
    for (int j = 0; j < 2; j++) acc[i][j] = (f32x16)0.f;

  // ---- staging geometry: thread t stages chunk (t&3) of rows t/4, t/4+128 ----
  const int srow = t >> 2;            // 0..127
  const int c16 = t & 3;
  const i64 srcR0 = (i64)srow * K + ((c16 ^ swz(srow)) << 4);
  const i64 srcR1 = (i64)(srow + 128) * K + ((c16 ^ swz(srow + 128)) << 4);
  const uint8_t* gA = Aq + (i64)(bm * BM) * K;
  const uint8_t* gB = Bq + (i64)(bn * BN) * K;
  const int d0 = t * 16;              // LDS dest round 0
  const int d1 = t * 16 + 8192;       // LDS dest round 1

  // ---- fragment read offsets within a tile (hoisted) ----
  int aoff[4][2], boff[2][2];
#pragma unroll
  for (int i = 0; i < 4; i++) {
    const int ra = wm + i * 32 + r31;
    const int sa_ = swz(ra);
    aoff[i][0] = ra * 64 + (((2 * g + 0) ^ sa_) << 4);
    aoff[i][1] = ra * 64 + (((2 * g + 1) ^ sa_) << 4);
  }
#pragma unroll
  for (int j = 0; j < 2; j++) {
    const int rb = wn + j * 32 + r31;
    const int sb_ = swz(rb);
    boff[j][0] = rb * 64 + (((2 * g + 0) ^ sb_) << 4);
    boff[j][1] = rb * 64 + (((2 * g + 1) ^ sb_) << 4);
  }

  const int NTI = K / 128;            // iterations (2 K-tiles each)

  // prologue: stage tiles 0,1 into slots 0,1 (8 gloads/thread in flight)
  gload_lds16(gA + srcR0, &sA[0][d0]);
  gload_lds16(gA + srcR1, &sA[0][d1]);
  gload_lds16(gB + srcR0, &sB[0][d0]);
  gload_lds16(gB + srcR1, &sB[0][d1]);
  gload_lds16(gA + srcR0 + 64, &sA[1][d0]);
  gload_lds16(gA + srcR1 + 64, &sA[1][d1]);
  gload_lds16(gB + srcR0 + 64, &sB[1][d0]);
  gload_lds16(gB + srcR1 + 64, &sB[1][d1]);
  asm volatile("s_waitcnt vmcnt(4)" ::: "memory");   // slot-0 tiles landed
  __builtin_amdgcn_s_barrier();

#define RD_A(slot, i, h) (*(const i32x4*)(&sA[slot][0] + aoff[i][h]))
#define RD_B(slot, j, h) (*(const i32x4*)(&sB[slot][0] + boff[j][h]))
#define MFMA2(ci, cj, uai, ubj)                                              \
  acc[ci][cj] = __builtin_amdgcn_mfma_scale_f32_32x32x64_f8f6f4(             \
      uai.v, ubj.v, acc[ci][cj], 0, 0, 0, 127, 0, 127);
#define BAR() __builtin_amdgcn_s_barrier()
#define PRIO1() __builtin_amdgcn_s_setprio(1)
#define PRIO0() __builtin_amdgcn_s_setprio(0)

  // one K-tile = 4 phases, column-pair order; FW = trailing wait
#define KTILE(RS, GL0, GL1, GL2, GL3, FW)                                    \
  {                                                                          \
    union opnd { i32x4 h[2]; i32x8 v; };                                     \
    union opnd ub0, ub1, ua;                                                 \
    ub0.h[0] = RD_B(RS, 0, 0); ub0.h[1] = RD_B(RS, 0, 1);                    \
    ub1.h[0] = RD_B(RS, 1, 0); ub1.h[1] = RD_B(RS, 1, 1);                    \
    ua.h[0]  = RD_A(RS, 0, 0); ua.h[1]  = RD_A(RS, 0, 1);                    \
    GL0;                                                                     \
    BAR(); PRIO1(); MFMA2(0, 0, ua, ub0); MFMA2(0, 1, ua, ub1);              \
    PRIO0(); BAR();                                                          \
    ua.h[0] = RD_A(RS, 1, 0); ua.h[1] = RD_A(RS, 1, 1);                      \
    GL1;                                                                     \
    BAR(); PRIO1(); MFMA2(1, 0, ua, ub0); MFMA2(1, 1, ua, ub1);              \
    PRIO0(); BAR();                                                          \
    ua.h[0] = RD_A(RS, 2, 0); ua.h[1] = RD_A(RS, 2, 1);                      \
    GL2;                                                                     \
    BAR(); PRIO1(); MFMA2(2, 0, ua, ub0); MFMA2(2, 1, ua, ub1);              \
    PRIO0(); BAR();                                                          \
    ua.h[0] = RD_A(RS, 3, 0); ua.h[1] = RD_A(RS, 3, 1);                      \
    GL3;                                                                     \
    BAR(); PRIO1(); MFMA2(3, 0, ua, ub0); MFMA2(3, 1, ua, ub1);              \
    PRIO0(); FW; BAR();                                                      \
  }

  for (int it = 0; it < NTI; ++it) {
    const int rs = (it & 1) << 1;        // read slots rs, rs+1
    const int ws_ = ((it & 1) ^ 1) << 1; // stage slots ws_, ws_+1
    const bool pf = (it + 1 < NTI);
    const i64 k0 = (i64)(it + 1) * 128;  // next iter's first tile k-offset

    if (pf) {
      KTILE(rs,
            gload_lds16(gA + srcR0 + k0, &sA[ws_][d0]),
            gload_lds16(gA + srcR1 + k0, &sA[ws_][d1]),
            gload_lds16(gB + srcR0 + k0, &sB[ws_][d0]),
            gload_lds16(gB + srcR1 + k0, &sB[ws_][d1]),
            asm volatile("s_waitcnt vmcnt(4)" ::: "memory"));
      KTILE(rs + 1,
            gload_lds16(gA + srcR0 + k0 + 64, &sA[ws_ + 1][d0]),
            gload_lds16(gA + srcR1 + k0 + 64, &sA[ws_ + 1][d1]),
            gload_lds16(gB + srcR0 + k0 + 64, &sB[ws_ + 1][d0]),
            gload_lds16(gB + srcR1 + k0 + 64, &sB[ws_ + 1][d1]),
            asm volatile("s_waitcnt vmcnt(4)" ::: "memory"));
    } else {
      KTILE(rs, , , , ,
            asm volatile("s_waitcnt vmcnt(0)" ::: "memory"));
      KTILE(rs + 1, , , , , );
    }
  }

  // ---- epilogue: bf16_rne(acc*(sx*sw) + bias) stored as FP32 -------------
  // 32x32 C/D layout (m74/m101): col = lane&31, row = (reg&3)+8*(reg>>2)+4*g
  const float sc = xs[0] * wsc[0];
#pragma unroll
  for (int j = 0; j < 2; j++) {
    const int col = bn * BN + wn + j * 32 + r31;
    const float bv = bias[col];
#pragma unroll
    for (int i = 0; i < 4; i++) {
      const int rowbase = bm * BM + wm + i * 32 + 4 * g;
#pragma unroll
      for (int reg = 0; reg < 16; reg++) {
        const int row = rowbase + (reg & 3) + 8 * (reg >> 2);
        C[(i64)row * N + col] = bf16_rne_f32(acc[i][j][reg] * sc + bv);
      }
    }
  }
}

extern "C" void kernel_launch(void* const* d_in, const int* in_sizes, int n_in,
                              void* d_out, int out_size, void* d_ws, size_t ws_size,
                              hipStream_t stream) {
  // Verified I/O model (R11 oracle + R12-R21 passes): declared order, element
  // counts, ALL buffers fp32-stored bf16-valued, output fp32.
  const float* x = (const float*)d_in[0];
  const float* w = (const float*)d_in[1];
  const float* bias = (const float*)d_in[2];
  const float* x_scale = (const float*)d_in[3];
  const float* w_scale = (const float*)d_in[4];

  const int N = in_sizes[2];
  const int K = in_sizes[1] / N;
  const int M = in_sizes[0] / K;

  uint8_t* xq = (uint8_t*)d_ws;                     // M*K = 32 MB
  uint8_t* wq = (uint8_t*)d_ws + (size_t)M * K;     // N*K = 64 MB

  {
    const int n16 = (M * K) / 16;
    quant_fp8_from_f32<<<(n16 + 255) / 256, 256, 0, stream>>>(x, x_scale, xq, n16);
  }
  {
    const int n16 = (int)(((i64)N * K) / 16);
    quant_fp8_from_f32<<<(n16 + 255) / 256, 256, 0, stream>>>(w, w_scale, wq, n16);
  }

  dim3 grid((M / BM) * (N / BN));
  gemm_fp8_mx<<<grid, 512, 0, stream>>>(
      xq, wq, bias, x_scale, w_scale, (float*)d_out, M, N, K);
}

// Round 23
// 822.706 us; speedup vs baseline: 5.2525x; 3.2318x over previous
//
#include <hip/hip_runtime.h>
#include <hip/hip_bf16.h>
#include <stdint.h>

typedef float f32x4 __attribute__((ext_vector_type(4)));
typedef float f32x16 __attribute__((ext_vector_type(16)));
typedef int i32x4 __attribute__((ext_vector_type(4)));
typedef int i32x8 __attribute__((ext_vector_type(8)));
typedef long i64;

#define BM 128
#define BN 128
#define BKB 64   // K elements (=bytes, fp8) per tile step

// 16B-chunk slot = chunk ^ swz(row); period 16 covers the 32-row frag read.
__device__ __host__ __forceinline__ int swz(int r) {
  return ((r >> 1) ^ (r >> 3)) & 3;
}

// ---------------- pre-quant: fp32 (bf16-valued) -> fp8 e4m3fn, LINEAR -------
__global__ __launch_bounds__(256) void quant_fp8_from_f32(
    const float* __restrict__ in, const float* __restrict__ scale,
    uint8_t* __restrict__ out, int n16) {
  const int i = blockIdx.x * blockDim.x + threadIdx.x;
  if (i >= n16) return;
  const float inv_s = 1.0f / scale[0];
  const float* p = in + (i64)i * 16;
  f32x4 v[4];
  v[0] = *(const f32x4*)p;
  v[1] = *(const f32x4*)(p + 4);
  v[2] = *(const f32x4*)(p + 8);
  v[3] = *(const f32x4*)(p + 12);
  uint32_t w[4];
#pragma unroll
  for (int q = 0; q < 4; q++) {
    float f0 = fminf(fmaxf(v[q][0] * inv_s, -448.f), 448.f);
    float f1 = fminf(fmaxf(v[q][1] * inv_s, -448.f), 448.f);
    float f2 = fminf(fmaxf(v[q][2] * inv_s, -448.f), 448.f);
    float f3 = fminf(fmaxf(v[q][3] * inv_s, -448.f), 448.f);
    int r = 0;
    r = __builtin_amdgcn_cvt_pk_fp8_f32(f0, f1, r, false);
    r = __builtin_amdgcn_cvt_pk_fp8_f32(f2, f3, r, true);
    w[q] = (uint32_t)r;
  }
  ((uint4*)out)[i] = make_uint4(w[0], w[1], w[2], w[3]);
}

__device__ __forceinline__ void gload_lds16(const void* g, void* l) {
  __builtin_amdgcn_global_load_lds(
      (const __attribute__((address_space(1))) uint32_t*)g,
      (__attribute__((address_space(3))) uint32_t*)l, 16, 0, 0);
}

__device__ __forceinline__ float bf16_rne_f32(float f) {
  union { float f; uint32_t u; } c; c.f = f;
  uint32_t lsb = (c.u >> 16) & 1u;
  c.u += 0x7FFFu + lsb;
  c.u &= 0xFFFF0000u;
  return c.f;
}

// ---------------- fp8 GEMM via MX-scaled 32x32x64 MFMA (scales = 1.0) -------
// 128x128 tile, 4 waves (2x2), wave-tile 64x64, acc[2][2] f32x16 (64 AGPR).
// Small per-wave state (~150 regs total) -> __launch_bounds__(256,3) ->
// 3 blocks/CU co-resident (96 KB LDS): cross-block async overlap hides the
// read/stage latency that the 1-block/CU lockstep (R19: 32% MfmaUtil) could
// not. Loop = R19-proven: [stage next (4 gloads/thread); vmcnt(4); barrier;
// ds_read+MFMA; barrier]. vmcnt counts per-THREAD instructions (R18 lesson).
__global__ __launch_bounds__(256, 3) void gemm_fp8_mx(
    const uint8_t* __restrict__ Aq, const uint8_t* __restrict__ Bq,
    const float* __restrict__ bias,
    const float* __restrict__ xs, const float* __restrict__ wsc,
    float* __restrict__ C, int M, int N, int K) {
  __shared__ uint8_t sA[2][BM * BKB];   // 2 x 8 KB
  __shared__ uint8_t sB[2][BN * BKB];   // 2 x 8 KB

  const int nbn = N / BN;
  int bid = blockIdx.x;
  { int cpx = gridDim.x >> 3; bid = (bid & 7) * cpx + (bid >> 3); }  // XCD swizzle
  const int bm = bid / nbn;
  const int bn = bid % nbn;

  const int t = threadIdx.x, lane = t & 63, wave = t >> 6;
  const int wm = (wave >> 1) * 64;    // 2x2 waves, 64x64 each
  const int wn = (wave & 1) * 64;
  const int g = lane >> 5;            // K-half group
  const int r31 = lane & 31;

  f32x16 acc[2][2];
#pragma unroll
  for (int i = 0; i < 2; i++)
#pragma unroll
    for (int j = 0; j < 2; j++) acc[i][j] = (f32x16)0.f;

  // ---- staging: thread t stages chunk (t&3) of rows t/4 and t/4+64 ----
  // LDS dest = t*16 (+4096): lane-stride 16 B = global_load_lds HW pattern.
  const int srow = t >> 2;            // 0..63
  const int c16 = t & 3;
  const i64 src0 = (i64)srow * K + ((c16 ^ swz(srow)) << 4);
  const i64 src1 = (i64)(srow + 64) * K + ((c16 ^ swz(srow + 64)) << 4);
  const uint8_t* gA = Aq + (i64)(bm * BM) * K;
  const uint8_t* gB = Bq + (i64)(bn * BN) * K;

  // ---- fragment read offsets (hoisted) ----
  int aoff[2][2], boff[2][2];
#pragma unroll
  for (int i = 0; i < 2; i++) {
    const int ra = wm + i * 32 + r31;
    const int sa_ = swz(ra);
    aoff[i][0] = ra * 64 + (((2 * g + 0) ^ sa_) << 4);
    aoff[i][1] = ra * 64 + (((2 * g + 1) ^ sa_) << 4);
    const int rb = wn + i * 32 + r31;
    const int sb_ = swz(rb);
    boff[i][0] = rb * 64 + (((2 * g + 0) ^ sb_) << 4);
    boff[i][1] = rb * 64 + (((2 * g + 1) ^ sb_) << 4);
  }

  const int NT = K / BKB;
  // prologue: stage tile 0 into buffer 0 (4 loads/thread in flight)
  gload_lds16(gA + src0, &sA[0][t * 16]);
  gload_lds16(gA + src1, &sA[0][t * 16 + 4096]);
  gload_lds16(gB + src0, &sB[0][t * 16]);
  gload_lds16(gB + src1, &sB[0][t * 16 + 4096]);

  int cur = 0;
  for (int it = 0; it < NT; ++it) {
    if (it + 1 < NT) {
      // issue next tile's 4 loads; they stay in flight across the barrier
      const i64 kt = (i64)(it + 1) * BKB;
      const int nxt = cur ^ 1;
      gload_lds16(gA + src0 + kt, &sA[nxt][t * 16]);
      gload_lds16(gA + src1 + kt, &sA[nxt][t * 16 + 4096]);
      gload_lds16(gB + src0 + kt, &sB[nxt][t * 16]);
      gload_lds16(gB + src1 + kt, &sB[nxt][t * 16 + 4096]);
      asm volatile("s_waitcnt vmcnt(4)" ::: "memory");   // current tile landed
    } else {
      asm volatile("s_waitcnt vmcnt(0)" ::: "memory");   // final tile landed
    }
    __builtin_amdgcn_s_barrier();   // collective: tile `it` fully in LDS

    union { i32x4 h[2]; i32x8 v; } ua[2], ub[2];
#pragma unroll
    for (int i = 0; i < 2; i++) {
      ua[i].h[0] = *(const i32x4*)(&sA[cur][0] + aoff[i][0]);
      ua[i].h[1] = *(const i32x4*)(&sA[cur][0] + aoff[i][1]);
      ub[i].h[0] = *(const i32x4*)(&sB[cur][0] + boff[i][0]);
      ub[i].h[1] = *(const i32x4*)(&sB[cur][0] + boff[i][1]);
    }
#pragma unroll
    for (int i = 0; i < 2; i++)
#pragma unroll
      for (int j = 0; j < 2; j++)
        acc[i][j] = __builtin_amdgcn_mfma_scale_f32_32x32x64_f8f6f4(
            ua[i].v, ub[j].v, acc[i][j],
            0, 0,          // cbsz=fp8(e4m3), blgp=fp8(e4m3)
            0, 127,        // scale_a = e8m0 1.0
            0, 127);       // scale_b = e8m0 1.0

    // all waves consumed their reads of buf[cur] before passing this barrier
    // (MFMA issue requires the compiler-inserted lgkmcnt wait); next iter may
    // then overwrite buf[cur^1]... staged buffer is cur^1, read next iter.
    __builtin_amdgcn_s_barrier();
    cur ^= 1;
  }

  // ---- epilogue: bf16_rne(acc*(sx*sw) + bias) stored as FP32 -------------
  // 32x32 C/D layout (m74/m101): col = lane&31, row = (reg&3)+8*(reg>>2)+4*g
  const float sc = xs[0] * wsc[0];
#pragma unroll
  for (int j = 0; j < 2; j++) {
    const int col = bn * BN + wn + j * 32 + r31;
    const float bv = bias[col];
#pragma unroll
    for (int i = 0; i < 2; i++) {
      const int rowbase = bm * BM + wm + i * 32 + 4 * g;
#pragma unroll
      for (int reg = 0; reg < 16; reg++) {
        const int row = rowbase + (reg & 3) + 8 * (reg >> 2);
        C[(i64)row * N + col] = bf16_rne_f32(acc[i][j][reg] * sc + bv);
      }
    }
  }
}

extern "C" void kernel_launch(void* const* d_in, const int* in_sizes, int n_in,
                              void* d_out, int out_size, void* d_ws, size_t ws_size,
                              hipStream_t stream) {
  // Verified I/O model (R11 oracle + R12-R22 passes): declared order, element
  // counts, ALL buffers fp32-stored bf16-valued, output fp32.
  const float* x = (const float*)d_in[0];
  const float* w = (const float*)d_in[1];
  const float* bias = (const float*)d_in[2];
  const float* x_scale = (const float*)d_in[3];
  const float* w_scale = (const float*)d_in[4];

  const int N = in_sizes[2];
  const int K = in_sizes[1] / N;
  const int M = in_sizes[0] / K;

  uint8_t* xq = (uint8_t*)d_ws;                     // M*K = 32 MB
  uint8_t* wq = (uint8_t*)d_ws + (size_t)M * K;     // N*K = 64 MB

  {
    const int n16 = (M * K) / 16;
    quant_fp8_from_f32<<<(n16 + 255) / 256, 256, 0, stream>>>(x, x_scale, xq, n16);
  }
  {
    const int n16 = (int)(((i64)N * K) / 16);
    quant_fp8_from_f32<<<(n16 + 255) / 256, 256, 0, stream>>>(w, w_scale, wq, n16);
  }

  dim3 grid((M / BM) * (N / BN));
  gemm_fp8_mx<<<grid, 256, 0, stream>>>(
      xq, wq, bias, x_scale, w_scale, (float*)d_out, M, N, K);
}